// Round 8
// baseline (110.059 us; speedup 1.0000x reference)
//
#include <hip/hip_runtime.h>
#include <stdint.h>

#define BB    4
#define CC    320
#define HH    135
#define WW    240
#define HW    (HH*WW)      // 32400
#define PNUM  12960
#define NBUCK 16384
#define MAXPER 32
#define P4    (HW/4)       // 8100
#define NCH   4
#define NCG   (CC/NCH)     // 80
#define NTILE (NCG*P4)     // 648000 (fallback path)
#define OCT   (HW/8)       // 4050
#define NF4   (BB*CC*HW/4) // 10,368,000 float4s in out
#define NBLK  512
#define PERB  (NF4/NBLK)   // 20250

typedef float f4 __attribute__((ext_vector_type(4)));
typedef unsigned u4 __attribute__((ext_vector_type(4)));
typedef unsigned short us8 __attribute__((ext_vector_type(8)));

__device__ inline unsigned short f2bf(float x) {   // round-to-nearest-even
    unsigned u = __float_as_uint(x);
    return (unsigned short)((u + 0x7fffu + ((u >> 16) & 1u)) >> 16);
}

// ---- Pass 0: zero the histogram ----
__global__ __launch_bounds__(256) void k_zero(unsigned* __restrict__ hist) {
    int i = blockIdx.x * 256 + threadIdx.x;
    if (i < NBUCK) hist[i] = 0u;
}

// ---- Pass 1: bucket each pixel by value ----
__global__ __launch_bounds__(256) void k_bucket(const float* __restrict__ unc,
                                                unsigned* __restrict__ hist,
                                                unsigned* __restrict__ members) {
    int i = blockIdx.x * 256 + threadIdx.x;
    if (i >= HW) return;
    float v = unc[i];
    int b = (int)(v * (float)NBUCK);
    b = b < 0 ? 0 : (b > NBUCK - 1 ? NBUCK - 1 : b);
    unsigned pos = atomicAdd(&hist[b], 1u);
    if (pos < MAXPER) members[(unsigned)b * MAXPER + pos] = (unsigned)i;
}

// ---- Pass 2: suffix-count ----
__global__ __launch_bounds__(1024) void k_scan(const unsigned* __restrict__ hist,
                                               unsigned* __restrict__ base) {
    __shared__ unsigned sh[1024];
    const int CH = NBUCK / 1024;
    int t = threadIdx.x;
    unsigned loc[CH];
    unsigned s = 0;
    #pragma unroll
    for (int k = 0; k < CH; ++k) { loc[k] = hist[t * CH + k]; s += loc[k]; }
    sh[t] = s;
    __syncthreads();
    for (int off = 1; off < 1024; off <<= 1) {
        unsigned v = (t + off < 1024) ? sh[t + off] : 0u;
        __syncthreads();
        sh[t] += v;
        __syncthreads();
    }
    unsigned run = sh[t] - s;
    #pragma unroll
    for (int k = CH - 1; k >= 0; --k) { base[t * CH + k] = run; run += loc[k]; }
}

// ---- Pass 3: exact descending rank, (value desc, index asc) tie-break ----
__global__ __launch_bounds__(256) void k_rank(const float* __restrict__ unc,
                                              const unsigned* __restrict__ hist,
                                              const unsigned* __restrict__ base,
                                              const unsigned* __restrict__ members,
                                              unsigned* __restrict__ rank) {
    int i = blockIdx.x * 256 + threadIdx.x;
    if (i >= HW) return;
    float vi = unc[i];
    int b = (int)(vi * (float)NBUCK);
    b = b < 0 ? 0 : (b > NBUCK - 1 ? NBUCK - 1 : b);
    unsigned cnt = hist[b];
    if (cnt > MAXPER) cnt = MAXPER;
    unsigned r = base[b];
    for (unsigned k = 0; k < cnt; ++k) {
        unsigned j = members[(unsigned)b * MAXPER + k];
        if (j == (unsigned)i) continue;
        float vj = unc[j];
        r += (vj > vi) || (vj == vi && j < (unsigned)i);
    }
    rank[i] = r;
}

// ---- Pass 4a: materialize bf16 delta as channel planes dbufp[c][p] ----
__global__ __launch_bounds__(256) void k_gather(const float* __restrict__ prompts,
                                                const unsigned* __restrict__ rank,
                                                unsigned short* __restrict__ dbufp) {
    int t = blockIdx.x * 256 + threadIdx.x;
    if (t >= NCG * OCT) return;
    int cg = t / OCT;
    int o8 = t - cg * OCT;
    int p0 = o8 * 8;

    u4 ra = *(const u4*)(rank + p0);
    u4 rb = *(const u4*)(rank + p0 + 4);

    unsigned short w[NCH][8];
    #pragma unroll
    for (int k = 0; k < 8; ++k) {
        unsigned r = (k < 4) ? ra[k] : rb[k - 4];
        f4 gv = (f4)(0.0f);
        if (r < PNUM) gv = *(const f4*)(prompts + (size_t)r * CC + cg * 4);
        #pragma unroll
        for (int j = 0; j < NCH; ++j) w[j][k] = f2bf(gv[j]);
    }
    #pragma unroll
    for (int j = 0; j < NCH; ++j) {
        us8 v;
        #pragma unroll
        for (int k = 0; k < 8; ++k) v[k] = w[j][k];
        *(us8*)(dbufp + (size_t)(cg * NCH + j) * HW + p0) = v;
    }
}

// ---- Pass 4b: LOW-STREAM-COUNT blocked-sequential apply ----
// 512 blocks, each owns a contiguous 20250-float4 region of out and walks it
// sequentially (4 f4/thread/iter, load-phase then store-phase). 2048 waves
// total, each a deep sequential stream -> DRAM row locality like the 7.1TB/s
// fill, instead of ~10k interleaved strided streams.
__global__ __launch_bounds__(256) void k_apply4(const float* __restrict__ x,
                                                const unsigned short* __restrict__ dbufp,
                                                float* __restrict__ out) {
    int start = blockIdx.x * PERB;
    int end   = start + PERB;

    int i = start + (int)threadIdx.x;
    for (; i + 768 < end; i += 1024) {
        f4 xv[4];
        uint2 dv[4];
        #pragma unroll
        for (int s = 0; s < 4; ++s) {
            int idx = i + s * 256;
            unsigned slice = (unsigned)idx / (unsigned)P4;       // b*CC+c
            unsigned rem   = (unsigned)idx - slice * P4;         // f4 within slice
            unsigned ch    = slice % (unsigned)CC;
            dv[s] = *(const uint2*)(dbufp + (size_t)ch * HW + 4 * (size_t)rem);
            xv[s] = *(const f4*)(x + 4 * (size_t)idx);
        }
        #pragma unroll
        for (int s = 0; s < 4; ++s) {
            f4 v = xv[s];
            v[0] += __uint_as_float(dv[s].x << 16);
            v[1] += __uint_as_float(dv[s].x & 0xffff0000u);
            v[2] += __uint_as_float(dv[s].y << 16);
            v[3] += __uint_as_float(dv[s].y & 0xffff0000u);
            *(f4*)(out + 4 * (size_t)(i + s * 256)) = v;
        }
    }
    for (; i < end; i += 256) {
        unsigned slice = (unsigned)i / (unsigned)P4;
        unsigned rem   = (unsigned)i - slice * P4;
        unsigned ch    = slice % (unsigned)CC;
        uint2 d = *(const uint2*)(dbufp + (size_t)ch * HW + 4 * (size_t)rem);
        f4 v = *(const f4*)(x + 4 * (size_t)i);
        v[0] += __uint_as_float(d.x << 16);
        v[1] += __uint_as_float(d.x & 0xffff0000u);
        v[2] += __uint_as_float(d.y << 16);
        v[3] += __uint_as_float(d.y & 0xffff0000u);
        *(f4*)(out + 4 * (size_t)i) = v;
    }
}

// ---- Fallback single-pass (R4 path) if ws too small ----
__global__ __launch_bounds__(256) void k_apply1(const float* __restrict__ x,
                                                const float* __restrict__ prompts,
                                                const unsigned* __restrict__ rank,
                                                float* __restrict__ out) {
    int t = blockIdx.x * 256 + threadIdx.x;
    if (t >= NTILE) return;
    int cg = t / P4;
    int p4 = t - cg * P4;
    int c0 = cg * NCH;
    int p  = p4 * 4;
    u4 r4 = *(const u4*)(rank + p);
    float g[4][NCH];
    #pragma unroll
    for (int k = 0; k < 4; ++k) {
        unsigned r = r4[k];
        f4 gv = (f4)(0.0f);
        if (r < PNUM) gv = *(const f4*)(prompts + (size_t)r * CC + c0);
        #pragma unroll
        for (int j = 0; j < NCH; ++j) g[k][j] = gv[j];
    }
    #pragma unroll
    for (int b = 0; b < BB; ++b) {
        #pragma unroll
        for (int j = 0; j < NCH; ++j) {
            int off = (b * CC + c0 + j) * HW + p;
            f4 xv = __builtin_nontemporal_load((const f4*)(x + off));
            xv[0] += g[0][j]; xv[1] += g[1][j]; xv[2] += g[2][j]; xv[3] += g[3][j];
            __builtin_nontemporal_store(xv, (f4*)(out + off));
        }
    }
}

extern "C" void kernel_launch(void* const* d_in, const int* in_sizes, int n_in,
                              void* d_out, int out_size, void* d_ws, size_t ws_size,
                              hipStream_t stream) {
    const float* x       = (const float*)d_in[0];
    const float* unc     = (const float*)d_in[1];
    const float* prompts = (const float*)d_in[2];
    float* out = (float*)d_out;

    char* ws = (char*)d_ws;
    unsigned* hist         = (unsigned*)(ws);
    unsigned* base         = (unsigned*)(ws + 65536);
    unsigned* members      = (unsigned*)(ws + 131072);
    unsigned* rank         = (unsigned*)(ws + 131072 + 2097152);
    unsigned short* dbufp  = (unsigned short*)(ws + 131072 + 2097152 + 131072);
    const size_t need = 131072 + 2097152 + 131072 + (size_t)CC * HW * 2;  // ~23.1 MB

    k_zero<<<NBUCK / 256, 256, 0, stream>>>(hist);
    k_bucket<<<(HW + 255) / 256, 256, 0, stream>>>(unc, hist, members);
    k_scan<<<1, 1024, 0, stream>>>(hist, base);
    k_rank<<<(HW + 255) / 256, 256, 0, stream>>>(unc, hist, base, members, rank);

    if (ws_size >= need) {
        k_gather<<<(NCG * OCT + 255) / 256, 256, 0, stream>>>(prompts, rank, dbufp);
        k_apply4<<<NBLK, 256, 0, stream>>>(x, dbufp, out);
    } else {
        k_apply1<<<(NTILE + 255) / 256, 256, 0, stream>>>(x, prompts, rank, out);
    }
}

// Round 9
// 81.335 us; speedup vs baseline: 1.3532x; 1.3532x over previous
//
#include <hip/hip_runtime.h>
#include <stdint.h>

#define BB    4
#define CC    320
#define HH    135
#define WW    240
#define HW    (HH*WW)      // 32400
#define PNUM  12960
#define NBUCK 16384
#define MAXPER 32
#define P4    (HW/4)       // 8100
#define NCH   4
#define NCG   (CC/NCH)     // 80
#define NTILE (NCG*P4)     // 648000

typedef float f4 __attribute__((ext_vector_type(4)));
typedef unsigned u4 __attribute__((ext_vector_type(4)));

// ---- Pass 0: zero the histogram ----
__global__ __launch_bounds__(256) void k_zero(unsigned* __restrict__ hist) {
    int i = blockIdx.x * 256 + threadIdx.x;
    if (i < NBUCK) hist[i] = 0u;
}

// ---- Pass 1: bucket each pixel by value ----
__global__ __launch_bounds__(256) void k_bucket(const float* __restrict__ unc,
                                                unsigned* __restrict__ hist,
                                                unsigned* __restrict__ members) {
    int i = blockIdx.x * 256 + threadIdx.x;
    if (i >= HW) return;
    float v = unc[i];
    int b = (int)(v * (float)NBUCK);
    b = b < 0 ? 0 : (b > NBUCK - 1 ? NBUCK - 1 : b);
    unsigned pos = atomicAdd(&hist[b], 1u);
    if (pos < MAXPER) members[(unsigned)b * MAXPER + pos] = (unsigned)i;
}

// ---- Pass 2: suffix-count ----
__global__ __launch_bounds__(1024) void k_scan(const unsigned* __restrict__ hist,
                                               unsigned* __restrict__ base) {
    __shared__ unsigned sh[1024];
    const int CH = NBUCK / 1024;
    int t = threadIdx.x;
    unsigned loc[CH];
    unsigned s = 0;
    #pragma unroll
    for (int k = 0; k < CH; ++k) { loc[k] = hist[t * CH + k]; s += loc[k]; }
    sh[t] = s;
    __syncthreads();
    for (int off = 1; off < 1024; off <<= 1) {
        unsigned v = (t + off < 1024) ? sh[t + off] : 0u;
        __syncthreads();
        sh[t] += v;
        __syncthreads();
    }
    unsigned run = sh[t] - s;
    #pragma unroll
    for (int k = CH - 1; k >= 0; --k) { base[t * CH + k] = run; run += loc[k]; }
}

// ---- Pass 3: exact descending rank, (value desc, index asc) tie-break ----
__global__ __launch_bounds__(256) void k_rank(const float* __restrict__ unc,
                                              const unsigned* __restrict__ hist,
                                              const unsigned* __restrict__ base,
                                              const unsigned* __restrict__ members,
                                              unsigned* __restrict__ rank) {
    int i = blockIdx.x * 256 + threadIdx.x;
    if (i >= HW) return;
    float vi = unc[i];
    int b = (int)(vi * (float)NBUCK);
    b = b < 0 ? 0 : (b > NBUCK - 1 ? NBUCK - 1 : b);
    unsigned cnt = hist[b];
    if (cnt > MAXPER) cnt = MAXPER;
    unsigned r = base[b];
    for (unsigned k = 0; k < cnt; ++k) {
        unsigned j = members[(unsigned)b * MAXPER + k];
        if (j == (unsigned)i) continue;
        float vj = unc[j];
        r += (vj > vi) || (vj == vi && j < (unsigned)i);
    }
    rank[i] = r;
}

// ---- Pass 4: fused out = x + scatter(prompts) ----
// R4 tiling (4ch x 4pix x 4batch per thread, 648k threads, full occupancy).
// KEY CHANGE vs R4: PLAIN loads of x (allocate x in the 256MB Infinity Cache,
// x=166MB fits entirely) + NT stores of out (evict-first / no-allocate, so the
// write stream does not displace x). Steady-state graph replays should then
// read x from LLC and only pay HBM for the write stream.
__global__ __launch_bounds__(256) void k_apply(const float* __restrict__ x,
                                               const float* __restrict__ prompts,
                                               const unsigned* __restrict__ rank,
                                               float* __restrict__ out) {
    int t = blockIdx.x * 256 + threadIdx.x;
    if (t >= NTILE) return;
    int cg = t / P4;
    int p4 = t - cg * P4;
    int c0 = cg * NCH;
    int p  = p4 * 4;

    u4 r4 = *(const u4*)(rank + p);

    float g[4][NCH];
    #pragma unroll
    for (int k = 0; k < 4; ++k) {
        unsigned r = r4[k];
        f4 gv = (f4)(0.0f);
        if (r < PNUM) gv = *(const f4*)(prompts + (size_t)r * CC + c0);
        #pragma unroll
        for (int j = 0; j < NCH; ++j) g[k][j] = gv[j];
    }

    #pragma unroll
    for (int b = 0; b < BB; ++b) {
        #pragma unroll
        for (int j = 0; j < NCH; ++j) {
            int off = (b * CC + c0 + j) * HW + p;
            f4 xv = *(const f4*)(x + off);          // plain: LLC-allocating
            xv[0] += g[0][j]; xv[1] += g[1][j]; xv[2] += g[2][j]; xv[3] += g[3][j];
            __builtin_nontemporal_store(xv, (f4*)(out + off));  // NT: don't evict x
        }
    }
}

extern "C" void kernel_launch(void* const* d_in, const int* in_sizes, int n_in,
                              void* d_out, int out_size, void* d_ws, size_t ws_size,
                              hipStream_t stream) {
    const float* x       = (const float*)d_in[0];
    const float* unc     = (const float*)d_in[1];
    const float* prompts = (const float*)d_in[2];
    float* out = (float*)d_out;

    char* ws = (char*)d_ws;
    unsigned* hist    = (unsigned*)(ws);
    unsigned* base    = (unsigned*)(ws + 65536);
    unsigned* members = (unsigned*)(ws + 131072);
    unsigned* rank    = (unsigned*)(ws + 131072 + 2097152);

    k_zero<<<NBUCK / 256, 256, 0, stream>>>(hist);
    k_bucket<<<(HW + 255) / 256, 256, 0, stream>>>(unc, hist, members);
    k_scan<<<1, 1024, 0, stream>>>(hist, base);
    k_rank<<<(HW + 255) / 256, 256, 0, stream>>>(unc, hist, base, members, rank);
    k_apply<<<(NTILE + 255) / 256, 256, 0, stream>>>(x, prompts, rank, out);
}